// Round 1
// baseline (587.746 us; speedup 1.0000x reference)
//
#include <hip/hip_runtime.h>
#include <cstdint>

#define T_SEQ 40
#define NB    16384
#define NH    128
#define NROWS 136          // 128 recurrent rows + 8 input rows
#define ROWD  130          // dword stride per row (65 float2, 520 B: conflict-free b64 reads)
#define WPB   16           // waves (batch rows) per block
#define NTHR  (WPB * 64)

// ---- wave-wide sum of two floats via DPP (VALU pipe; keeps DS pipe free) ----
template <int C>
__device__ __forceinline__ float dppstep(float v) {
  int t = __builtin_amdgcn_update_dpp(0, __float_as_int(v), C, 0xF, 0xF, true);
  return v + __int_as_float(t);
}
__device__ __forceinline__ void wave_sum2(float &a, float &b) {
  a = dppstep<0x111>(a); b = dppstep<0x111>(b);   // row_shr:1
  a = dppstep<0x112>(a); b = dppstep<0x112>(b);   // row_shr:2
  a = dppstep<0x114>(a); b = dppstep<0x114>(b);   // row_shr:4
  a = dppstep<0x118>(a); b = dppstep<0x118>(b);   // row_shr:8  -> lane15/31/47/63 hold row sums
  a = dppstep<0x142>(a); b = dppstep<0x142>(b);   // row_bcast15
  a = dppstep<0x143>(a); b = dppstep<0x143>(b);   // row_bcast31 -> lane63 holds total
  a = __int_as_float(__builtin_amdgcn_readlane(__float_as_int(a), 63));
  b = __int_as_float(__builtin_amdgcn_readlane(__float_as_int(b), 63));
}

// scalar-uniform spike iterator over (even-h mask, odd-h mask, input mask).
// Yields LDS dword offset of the weight row, or -1 when exhausted.
#define NEXT_OFF(dst) do {                                                      \
    if (mE)      { int l_ = __builtin_ctzll(mE); mE &= mE - 1; dst = l_ * (2*ROWD); }        \
    else if (mO) { int l_ = __builtin_ctzll(mO); mO &= mO - 1; dst = l_ * (2*ROWD) + ROWD; } \
    else if (mI) { int l_ = __builtin_ctzll(mI); mI &= mI - 1; dst = (128 + l_) * ROWD; }    \
    else dst = -1;                                                              \
  } while (0)

__global__ __launch_bounds__(NTHR, 8)
void Policy_22033182228693_kernel(const float* __restrict__ x,
                                  const float* __restrict__ w_in,
                                  const float* __restrict__ w_rec,
                                  const float* __restrict__ w_out,
                                  const float* __restrict__ dmask,
                                  float* __restrict__ out)
{
  __shared__ float W[NROWS * ROWD];   // 70,720 B -> 2 blocks/CU

  const int tid = threadIdx.x;
  // Stage w_rec transposed: W[j][h] = w_rec[h][j]. Coalesced reads; LDS writes ~4-way (one-time).
  for (int e = tid; e < NH * NH; e += NTHR) {
    int h = e >> 7, j = e & 127;
    W[j * ROWD + h] = w_rec[e];
  }
  // Stage w_in transposed into rows 128..135: W[128+k][h] = w_in[h][k]
  for (int e = tid; e < NH * 8; e += NTHR) {
    int h = e >> 3, k = e & 7;
    W[(128 + k) * ROWD + h] = w_in[e];
  }
  __syncthreads();   // only barrier in the kernel

  const int wave  = tid >> 6;
  const int lane  = tid & 63;
  const int b     = blockIdx.x * WPB + wave;   // one batch row per wave
  const int lane2 = lane << 1;

  // Encoder constant current: lanes 0..3 -> relu(50*x[k]), lanes 4..7 -> relu(-50*x[k])
  float xv = x[(size_t)b * 4 + (lane & 3)];
  float cc = fmaxf(0.f, ((lane & 4) ? -50.f : 50.f) * xv);
  if (lane >= 8) cc = 0.f;

  // Readout weights for this lane's two neurons
  const float2 wo0 = ((const float2*)w_out)[lane];        // w_out[0][2l], w_out[0][2l+1]
  const float2 wo1 = ((const float2*)w_out)[64 + lane];   // w_out[1][2l], w_out[1][2l+1]

  // Dropout mask stream: float2 per lane per step, 2-deep prefetch
  const float2* gm = (const float2*)dmask + (size_t)b * 64 + lane;
  const size_t TS = (size_t)NB * 64;
  float2 mcur = gm[0];
  float2 mnxt = gm[TS];

  float ve = 0.f;                                  // encoder membrane
  float v0 = 0.f, v1 = 0.f, i0 = 0.f, i1 = 0.f;    // hidden LIF state (2 neurons/lane)
  float io0 = 0.f, io1 = 0.f, vo0 = 0.f, vo1 = 0.f;
  float m0 = -3.0e38f, m1 = -3.0e38f;
  uint64_t bE = 0, bO = 0;                         // previous-step spike ballots (carry z)

#pragma unroll 1
  for (int t = 0; t < T_SEQ; ++t) {
    // ---- encoder advance (produces xs[t]) ----
    ve += 0.1f * (cc - ve);
    bool zi = ve > 1.0f;
    if (zi) ve = 0.f;
    uint64_t bI = __ballot((int)zi);               // bits 0..7 = input channels

    // ---- hidden membrane (uses old i) ----
    float vd0 = v0 + 0.1f * (i0 - v0);
    float vd1 = v1 + 0.1f * (i1 - v1);
    bool z0 = vd0 > 1.0f, z1 = vd1 > 1.0f;
    v0 = z0 ? 0.f : vd0;
    v1 = z1 ? 0.f : vd1;

    // ---- synaptic current: decay + sparse column gather (prev z, current input) ----
    float a0 = 0.8f * i0, a1 = 0.8f * i1;
    {
      uint64_t mE = bE, mO = bO, mI = bI;
      int oA;
      NEXT_OFF(oA);
      if (oA >= 0) {                               // depth-1 SW pipeline on ds_read_b64
        float2 wA = *(const float2*)&W[oA + lane2];
        int oB; NEXT_OFF(oB);
        while (oB >= 0) {
          float2 wB = *(const float2*)&W[oB + lane2];
          a0 += wA.x; a1 += wA.y;
          wA = wB;
          NEXT_OFF(oB);
        }
        a0 += wA.x; a1 += wA.y;
      }
    }
    i0 = a0; i1 = a1;

    // ballots for next step's recurrent input
    bE = __ballot((int)z0);
    bO = __ballot((int)z1);

    // ---- dropout + readout ----
    float2 mt = mcur;
    mcur = mnxt;
    int tp = (t + 2 < T_SEQ) ? t + 2 : T_SEQ - 1;
    mnxt = gm[(size_t)tp * TS];

    float zd0 = z0 ? mt.x : 0.f;
    float zd1 = z1 ? mt.y : 0.f;
    float u0 = zd0 * wo0.x + zd1 * wo0.y;
    float u1 = zd0 * wo1.x + zd1 * wo1.y;
    if (bE | bO) {
      wave_sum2(u0, u1);
    } else {
      u0 = 0.f; u1 = 0.f;
    }

    vo0 += 0.1f * (io0 - vo0);                     // vo_new uses old io
    vo1 += 0.1f * (io1 - vo1);
    io0 = 0.8f * io0 + u0;
    io1 = 0.8f * io1 + u1;
    m0 = fmaxf(m0, vo0);
    m1 = fmaxf(m1, vo1);
  }

  if (lane == 0) {
    float mx = fmaxf(m0, m1);
    float e0 = expf(m0 - mx), e1 = expf(m1 - mx);
    float inv = 1.f / (e0 + e1);
    ((float2*)out)[b] = make_float2(e0 * inv, e1 * inv);
  }
}

extern "C" void kernel_launch(void* const* d_in, const int* in_sizes, int n_in,
                              void* d_out, int out_size, void* d_ws, size_t ws_size,
                              hipStream_t stream) {
  const float* x     = (const float*)d_in[0];
  const float* w_in  = (const float*)d_in[1];
  const float* w_rec = (const float*)d_in[2];
  const float* w_out = (const float*)d_in[3];
  const float* dmask = (const float*)d_in[4];
  float* out = (float*)d_out;

  dim3 grid(NB / WPB);   // 1024 blocks
  dim3 block(NTHR);      // 1024 threads = 16 waves = 16 batch rows
  hipLaunchKernelGGL(Policy_22033182228693_kernel, grid, block, 0, stream,
                     x, w_in, w_rec, w_out, dmask, out);
}